// Round 3
// baseline (239.489 us; speedup 1.0000x reference)
//
#include <hip/hip_runtime.h>

typedef __attribute__((ext_vector_type(8))) short bf16x8;
typedef __attribute__((ext_vector_type(4))) float f32x4;
typedef __attribute__((ext_vector_type(8))) unsigned short u16x8;
typedef unsigned int u32;
typedef unsigned short u16;

#define CIN 512
#define CO  512
#define HH  64
#define WW  64
#define BB  8
#define HP  66
#define WPAD 68
#define KK  4608  // CIN*9

#define SIG_BYTES  (BB*CO*4)                       // 16384
#define WMOD_ELEMS ((size_t)BB*9*64*CO*8)          // 18,874,368
#define WMOD_BYTES (WMOD_ELEMS*2)                  // 37,748,736
#define IMGT_ELEMS ((size_t)BB*HP*WPAD*CIN)        // 18,382,848
#define IMGT_BYTES (IMGT_ELEMS*2)                  // 36,765,696
#define WS_NEED    ((size_t)SIG_BYTES + WMOD_BYTES + IMGT_BYTES)

__device__ __forceinline__ u16 f2bf(float f) {
  union { float f; u32 u; } v; v.f = f;
  u32 r = (v.u + 0x7FFFu + ((v.u >> 16) & 1u)) >> 16;  // RNE
  return (u16)r;
}

// ---------------- K1: sigma[b][o] = rsqrt(sum_i,t (w*(s+1))^2 + eps) ----------
__global__ void k_sigma(const float* __restrict__ weight, const float* __restrict__ s,
                        float* __restrict__ sigma) {
  int o = blockIdx.x;          // 512 blocks
  int tid = threadIdx.x;       // 256 threads
  const float* wrow = weight + (size_t)o * KK;
  float acc[BB];
#pragma unroll
  for (int b = 0; b < BB; ++b) acc[b] = 0.f;
  for (int e = tid; e < KK; e += 256) {
    float w = wrow[e];
    float w2 = w * w;
    int i = e / 9;
#pragma unroll
    for (int b = 0; b < BB; ++b) {
      float m = s[b * CIN + i] + 1.0f;
      acc[b] += w2 * m * m;
    }
  }
#pragma unroll
  for (int b = 0; b < BB; ++b) {
#pragma unroll
    for (int off = 32; off >= 1; off >>= 1)
      acc[b] += __shfl_down(acc[b], off);
  }
  __shared__ float red[4][BB];
  int wv = tid >> 6, ln = tid & 63;
  if (ln == 0) {
#pragma unroll
    for (int b = 0; b < BB; ++b) red[wv][b] = acc[b];
  }
  __syncthreads();
  if (tid < BB) {
    float t = red[0][tid] + red[1][tid] + red[2][tid] + red[3][tid];
    sigma[tid * CO + o] = rsqrtf(t + 1e-8f);
  }
}

// ------------- K2: wmod[b][t][kg][o][8] bf16, LDS-staged coalesced ------------
__global__ __launch_bounds__(256) void k_wmod(const float* __restrict__ weight,
                                              const float* __restrict__ s,
                                              const float* __restrict__ sigma,
                                              u16* __restrict__ wmod) {
  __shared__ float lw[16][577];
  int bid = blockIdx.x;        // 256 = 32 oc * 8 ic
  int oc = bid & 31, ic = bid >> 5;
  int o0 = oc * 16;
  int tid = threadIdx.x;
  const float* wsrc = weight + (size_t)o0 * KK + ic * 576;
#pragma unroll
  for (int k = 0; k < 9; ++k) {
    int f4 = tid + k * 256;            // 0..2303
    int row = f4 / 144;                // 144 float4 per row
    int col = f4 - row * 144;
    float4 v = *(const float4*)(wsrc + (size_t)row * KK + col * 4);
    lw[row][col*4+0]=v.x; lw[row][col*4+1]=v.y; lw[row][col*4+2]=v.z; lw[row][col*4+3]=v.w;
  }
  __syncthreads();
  int o_l = tid & 15, kg_l = (tid >> 4) & 7;
#pragma unroll
  for (int k = 0; k < 36; ++k) {
    int bt = k * 2 + (tid >> 7);       // 0..71
    int b = bt / 9;
    int t = bt - b * 9;
    int o = o0 + o_l;
    float sig = sigma[b * CO + o];
    u16x8 ov;
#pragma unroll
    for (int j = 0; j < 8; ++j) {
      int il = kg_l * 8 + j;
      float w = lw[o_l][il * 9 + t];
      float m = s[b * CIN + ic * 64 + il] + 1.0f;
      ov[j] = f2bf(w * m * sig);
    }
    *(u16x8*)(wmod + ((size_t)(bt * 64 + (ic * 8 + kg_l)) * CO + o) * 8) = ov;
  }
}

// ------------- K3a: zero the pad border of imgt ------------------------------
__global__ void k_pad(u16* __restrict__ imgt) {
  int gid = blockIdx.x * 256 + threadIdx.x;   // 528*256 = 135168 vec-stores
  int c8 = gid & 63;
  int pos = gid >> 6;                         // 0..2111 = 8b * 264
  int b = pos / 264;
  int pr = pos - b * 264;
  int yp, xp;
  if (pr < 136) { yp = (pr < 68) ? 0 : 65; xp = (pr < 68) ? pr : pr - 68; }
  else { int q = pr - 136; yp = 1 + (q >> 1); xp = (q & 1) ? 67 : 0; }
  u16x8 z = {0,0,0,0,0,0,0,0};
  *(u16x8*)(imgt + (((size_t)b * HP + yp) * WPAD + xp) * CIN + c8 * 8) = z;
}

// ------------- K3b: imgt[b][yp(66)][xp(68)][i] bf16, interior ----------------
__global__ void k_imgt(const float* __restrict__ img, u16* __restrict__ imgt) {
  int bid = blockIdx.x;        // 8*64*2*8 = 8192 blocks
  int ic = bid & 7;  int r = bid >> 3;
  int xc = r & 1;    r >>= 1;
  int y  = r & 63;   int b = r >> 6;
  int tid = threadIdx.x;
  __shared__ float lt[64][33];
  {
    int ii = tid >> 2, xq = tid & 3;
    const float* src = img + (((size_t)(b * CIN + ic * 64 + ii)) * HH + y) * WW + xc * 32 + xq * 8;
    float4 v0 = *(const float4*)src;
    float4 v1 = *(const float4*)(src + 4);
    int xb = xq * 8;
    lt[ii][xb+0]=v0.x; lt[ii][xb+1]=v0.y; lt[ii][xb+2]=v0.z; lt[ii][xb+3]=v0.w;
    lt[ii][xb+4]=v1.x; lt[ii][xb+5]=v1.y; lt[ii][xb+6]=v1.z; lt[ii][xb+7]=v1.w;
  }
  __syncthreads();
  int xl = tid >> 3, iq = tid & 7;
  u16x8 ov;
#pragma unroll
  for (int j = 0; j < 8; ++j) ov[j] = f2bf(lt[iq*8+j][xl]);
  size_t dst = (((size_t)b * HP + (y + 1)) * WPAD + (xc * 32 + xl + 1)) * CIN + ic * 64 + iq * 8;
  *(u16x8*)(imgt + dst) = ov;
}

// ------- K4: implicit-GEMM conv, per-wave 128x64, block 256o x 128pos ---------
__device__ __forceinline__ void async16(const u16* g, void* lds) {
  __builtin_amdgcn_global_load_lds((const __attribute__((address_space(1))) u32*)g,
                                   (__attribute__((address_space(3))) u32*)lds, 16, 0, 0);
}

__global__ __launch_bounds__(256, 2) void k_conv(const u16* __restrict__ wmod,
                                                 const u16* __restrict__ imgt,
                                                 float* __restrict__ out) {
  __shared__ alignas(16) char tile[2][17408];   // dbuf: 272 positions x 64B (swizzled)
  int bid0 = blockIdx.x;                        // 512 = 8b * 2ot * 32pt
  int bid  = (bid0 & 7) * 64 + (bid0 >> 3);     // XCD-chunked: each XCD = one batch
  int b   = bid >> 6;
  int rem = bid & 63;
  int ot  = rem >> 5;
  int pt  = rem & 31;
  int y0    = pt * 2;
  int obase = ot * 256;
  int tid = threadIdx.x;
  int wave = tid >> 6, lane = tid & 63;
  int wm = wave >> 1, wn = wave & 1;            // wm: o-half(128), wn: y-row
  int col0 = lane & 15, kg = lane >> 4;

  // Staging source offsets (inverse-swizzled global source, linear LDS dest).
  int srcoff[5];
#pragma unroll
  for (int jj = 0; jj < 5; ++jj) {
    int j = wave + jj * 4;
    if (j < 17) {
      int A = j * 1024 + lane * 16;
      int L = A ^ ((A >> 2) & 0x70) ^ ((A >> 4) & 0x10);
      int P = L >> 6;
      int sl = (L >> 4) & 3;
      int rr = P / 68;
      int cc = P - rr * 68;
      srcoff[jj] = ((b * HP + (y0 + rr)) * WPAD + cc) * CIN + sl * 8;
    } else srcoff[jj] = 0;
  }

#define STAGE(bufi, ic) do { \
  _Pragma("unroll") \
  for (int jj = 0; jj < 5; ++jj) { \
    int j = wave + jj * 4; \
    if (j < 17) async16(imgt + srcoff[jj] + (ic) * 32, (void*)(tile[bufi] + j * 1024)); \
  } } while (0)

  f32x4 zero = {0.f, 0.f, 0.f, 0.f};
  f32x4 acc[8][4];
#pragma unroll
  for (int i = 0; i < 8; ++i)
#pragma unroll
    for (int j = 0; j < 4; ++j) acc[i][j] = zero;

  const bf16x8* wv = (const bf16x8*)wmod;
  int abase = obase + wm * 128 + col0;   // o coordinate of am=0 fragment

  STAGE(0, 0);
  __syncthreads();

  for (int icc = 0; icc < 16; ++icc) {
    const char* curb = tile[icc & 1];
    if (icc < 15) STAGE((icc + 1) & 1, icc + 1);
#pragma unroll
    for (int t = 0; t < 9; ++t) {
      int ky = t / 3, kx = t - ky * 3;
      bf16x8 bv[4];
#pragma unroll
      for (int an = 0; an < 4; ++an) {
        int P = (wn + ky) * WPAD + an * 16 + col0 + kx;
        int L = P * 64 + kg * 16;
        bv[an] = *(const bf16x8*)(curb + (L ^ ((P & 7) << 4)));
      }
      int aidx = ((b * 9 + t) * 64 + icc * 4 + kg) * CO + abase;
#pragma unroll
      for (int am = 0; am < 8; ++am) {
        bf16x8 a = wv[aidx + am * 16];
        acc[am][0] = __builtin_amdgcn_mfma_f32_16x16x32_bf16(a, bv[0], acc[am][0], 0, 0, 0);
        acc[am][1] = __builtin_amdgcn_mfma_f32_16x16x32_bf16(a, bv[1], acc[am][1], 0, 0, 0);
        acc[am][2] = __builtin_amdgcn_mfma_f32_16x16x32_bf16(a, bv[2], acc[am][2], 0, 0, 0);
        acc[am][3] = __builtin_amdgcn_mfma_f32_16x16x32_bf16(a, bv[3], acc[am][3], 0, 0, 0);
      }
    }
    __syncthreads();   // drains stage vmcnt; buf[nxt] ready, buf[cur] reusable
  }
#undef STAGE

  int y = y0 + wn;
#pragma unroll
  for (int am = 0; am < 8; ++am) {
    int o = obase + wm * 128 + am * 16 + kg * 4;   // row = (lane>>4)*4 + reg
#pragma unroll
    for (int an = 0; an < 4; ++an) {
      int x = an * 16 + col0;                      // col = lane&15
      float* op = out + (((size_t)(b * CO + o)) * HH + y) * WW + x;
#pragma unroll
      for (int rg = 0; rg < 4; ++rg)
        op[(size_t)rg * HH * WW] = acc[am][an][rg];
    }
  }
}

// ---------------- Fallback (ws too small): naive but correct ------------------
__global__ void k_naive(const float* __restrict__ img, const float* __restrict__ s,
                        const float* __restrict__ weight, const float* __restrict__ sigma,
                        float* __restrict__ out) {
  int bid = blockIdx.x;          // 8*512*64, 64 threads
  int y = bid & 63; int r = bid >> 6; int o = r & 511; int b = r >> 9;
  int x = threadIdx.x;
  float sig = sigma[b * CO + o];
  float acc = 0.f;
  for (int i = 0; i < CIN; ++i) {
    float m = s[b * CIN + i] + 1.0f;
    const float* wp = weight + ((size_t)o * CIN + i) * 9;
    const float* ip = img + ((size_t)(b * CIN + i)) * HH * WW;
#pragma unroll
    for (int ky = 0; ky < 3; ++ky) {
      int yy = y + ky - 1;
      if (yy < 0 || yy > 63) continue;
#pragma unroll
      for (int kx = 0; kx < 3; ++kx) {
        int xx = x + kx - 1;
        float iv = (xx >= 0 && xx < 64) ? ip[yy * 64 + xx] : 0.f;
        acc += wp[ky * 3 + kx] * m * iv;
      }
    }
  }
  out[((size_t)(b * CO + o) * HH + y) * WW + x] = acc * sig;
}

extern "C" void kernel_launch(void* const* d_in, const int* in_sizes, int n_in,
                              void* d_out, int out_size, void* d_ws, size_t ws_size,
                              hipStream_t stream) {
  const float* img    = (const float*)d_in[0];
  const float* s      = (const float*)d_in[1];
  const float* weight = (const float*)d_in[2];
  float* out = (float*)d_out;
  char* ws = (char*)d_ws;
  float* sigma = (float*)ws;

  if (ws_size >= WS_NEED) {
    u16* wmod = (u16*)(ws + SIG_BYTES);
    u16* imgt = (u16*)(ws + SIG_BYTES + WMOD_BYTES);
    k_sigma<<<512, 256, 0, stream>>>(weight, s, sigma);
    k_wmod<<<256, 256, 0, stream>>>(weight, s, sigma, wmod);
    k_pad<<<528, 256, 0, stream>>>(imgt);
    k_imgt<<<8192, 256, 0, stream>>>(img, imgt);
    k_conv<<<512, 256, 0, stream>>>(wmod, imgt, out);
  } else {
    k_sigma<<<512, 256, 0, stream>>>(weight, s, sigma);
    k_naive<<<BB * CO * HH, 64, 0, stream>>>(img, s, weight, sigma, out);
  }
}

// Round 4
// 177.017 us; speedup vs baseline: 1.3529x; 1.3529x over previous
//
#include <hip/hip_runtime.h>

typedef __attribute__((ext_vector_type(8))) short bf16x8;
typedef __attribute__((ext_vector_type(4))) float f32x4;
typedef __attribute__((ext_vector_type(8))) unsigned short u16x8;
typedef unsigned int u32;
typedef unsigned short u16;

#define CIN 512
#define CO  512
#define HH  64
#define WW  64
#define BB  8
#define HP  66
#define WPAD 68
#define HPW (HP*WPAD)
#define KK  4608  // CIN*9

#define SIG_BYTES  (BB*CO*4)                       // 16384
#define WMOD_ELEMS ((size_t)BB*9*64*CO*8)          // 18,874,368
#define WMOD_BYTES (WMOD_ELEMS*2)                  // 37,748,736
#define IMGT_ELEMS ((size_t)BB*64*HP*WPAD*8)       // 18,382,848  [b][grp64][66][68][8]
#define IMGT_BYTES (IMGT_ELEMS*2)                  // 36,765,696
#define WS_NEED    ((size_t)SIG_BYTES + WMOD_BYTES + IMGT_BYTES)

__device__ __forceinline__ u16 f2bf(float f) {
  union { float f; u32 u; } v; v.f = f;
  u32 r = (v.u + 0x7FFFu + ((v.u >> 16) & 1u)) >> 16;  // RNE
  return (u16)r;
}

// ---------------- K1: sigma[b][o] = rsqrt(sum_i,t (w*(s+1))^2 + eps) ----------
__global__ void k_sigma(const float* __restrict__ weight, const float* __restrict__ s,
                        float* __restrict__ sigma) {
  int o = blockIdx.x;          // 512 blocks
  int tid = threadIdx.x;       // 256 threads
  const float* wrow = weight + (size_t)o * KK;
  float acc[BB];
#pragma unroll
  for (int b = 0; b < BB; ++b) acc[b] = 0.f;
  for (int e = tid; e < KK; e += 256) {
    float w = wrow[e];
    float w2 = w * w;
    int i = e / 9;
#pragma unroll
    for (int b = 0; b < BB; ++b) {
      float m = s[b * CIN + i] + 1.0f;
      acc[b] += w2 * m * m;
    }
  }
#pragma unroll
  for (int b = 0; b < BB; ++b) {
#pragma unroll
    for (int off = 32; off >= 1; off >>= 1)
      acc[b] += __shfl_down(acc[b], off);
  }
  __shared__ float red[4][BB];
  int wv = tid >> 6, ln = tid & 63;
  if (ln == 0) {
#pragma unroll
    for (int b = 0; b < BB; ++b) red[wv][b] = acc[b];
  }
  __syncthreads();
  if (tid < BB) {
    float t = red[0][tid] + red[1][tid] + red[2][tid] + red[3][tid];
    sigma[tid * CO + o] = rsqrtf(t + 1e-8f);
  }
}

// ------------- K2: wmod[b][t][kg][o][8] bf16, LDS-staged coalesced ------------
__global__ __launch_bounds__(256) void k_wmod(const float* __restrict__ weight,
                                              const float* __restrict__ s,
                                              const float* __restrict__ sigma,
                                              u16* __restrict__ wmod) {
  __shared__ float lw[16][577];
  int bid = blockIdx.x;        // 256 = 32 oc * 8 ic
  int oc = bid & 31, ic = bid >> 5;
  int o0 = oc * 16;
  int tid = threadIdx.x;
  const float* wsrc = weight + (size_t)o0 * KK + ic * 576;
#pragma unroll
  for (int k = 0; k < 9; ++k) {
    int f4 = tid + k * 256;            // 0..2303
    int row = f4 / 144;                // 144 float4 per row
    int col = f4 - row * 144;
    float4 v = *(const float4*)(wsrc + (size_t)row * KK + col * 4);
    lw[row][col*4+0]=v.x; lw[row][col*4+1]=v.y; lw[row][col*4+2]=v.z; lw[row][col*4+3]=v.w;
  }
  __syncthreads();
  int o_l = tid & 15, kg_l = (tid >> 4) & 7;
#pragma unroll
  for (int k = 0; k < 36; ++k) {
    int bt = k * 2 + (tid >> 7);       // 0..71
    int b = bt / 9;
    int t = bt - b * 9;
    int o = o0 + o_l;
    float sig = sigma[b * CO + o];
    u16x8 ov;
#pragma unroll
    for (int j = 0; j < 8; ++j) {
      int il = kg_l * 8 + j;
      float w = lw[o_l][il * 9 + t];
      float m = s[b * CIN + ic * 64 + il] + 1.0f;
      ov[j] = f2bf(w * m * sig);
    }
    *(u16x8*)(wmod + ((size_t)(bt * 64 + (ic * 8 + kg_l)) * CO + o) * 8) = ov;
  }
}

// ------------- K3a: zero pad border of imgt [b][grp][66][68][8] --------------
__global__ void k_pad(u16* __restrict__ imgt) {
  int gid = blockIdx.x * 256 + threadIdx.x;   // 528*256 = 135168 vec-stores
  int grp = gid & 63;
  int pos = gid >> 6;                         // 0..2111 = 8b * 264
  int b = pos / 264;
  int pr = pos - b * 264;
  int yp, xp;
  if (pr < 136) { yp = (pr < 68) ? 0 : 65; xp = (pr < 68) ? pr : pr - 68; }
  else { int q = pr - 136; yp = 1 + (q >> 1); xp = (q & 1) ? 67 : 0; }
  u16x8 z = {0,0,0,0,0,0,0,0};
  *(u16x8*)(imgt + (((size_t)(b * 64 + grp) * HP + yp) * WPAD + xp) * 8) = z;
}

// ------------- K3b: imgt[b][grp(64)][yp(66)][xp(68)][8ch] bf16, interior ------
__global__ void k_imgt(const float* __restrict__ img, u16* __restrict__ imgt) {
  int bid = blockIdx.x;        // 8*64*2*8 = 8192 blocks
  int ic = bid & 7;  int r = bid >> 3;
  int xc = r & 1;    r >>= 1;
  int y  = r & 63;   int b = r >> 6;
  int tid = threadIdx.x;
  __shared__ float lt[64][33];
  {
    int ii = tid >> 2, xq = tid & 3;
    const float* src = img + (((size_t)(b * CIN + ic * 64 + ii)) * HH + y) * WW + xc * 32 + xq * 8;
    float4 v0 = *(const float4*)src;
    float4 v1 = *(const float4*)(src + 4);
    int xb = xq * 8;
    lt[ii][xb+0]=v0.x; lt[ii][xb+1]=v0.y; lt[ii][xb+2]=v0.z; lt[ii][xb+3]=v0.w;
    lt[ii][xb+4]=v1.x; lt[ii][xb+5]=v1.y; lt[ii][xb+6]=v1.z; lt[ii][xb+7]=v1.w;
  }
  __syncthreads();
  int xl = tid >> 3, iq = tid & 7;
  u16x8 ov;
#pragma unroll
  for (int j = 0; j < 8; ++j) ov[j] = f2bf(lt[iq*8+j][xl]);
  size_t dst = (((size_t)(b * 64 + ic * 8 + iq) * HP + (y + 1)) * WPAD + (xc * 32 + xl + 1)) * 8;
  *(u16x8*)(imgt + dst) = ov;
}

// ------- K4: implicit-GEMM conv: A via LDS tri-buffer (async), B via reg pf ---
__device__ __forceinline__ void async16(const u16* g, void* lds) {
  __builtin_amdgcn_global_load_lds((const __attribute__((address_space(1))) u32*)g,
                                   (__attribute__((address_space(3))) u32*)lds, 16, 0, 0);
}

__global__ __launch_bounds__(512, 2) void k_conv(const u16* __restrict__ wmod,
                                                 const u16* __restrict__ imgt,
                                                 float* __restrict__ out) {
  __shared__ alignas(16) u16 abuf[3][8192];     // 3 x 16KB A-tiles (256o x 32ch)
  int bid = blockIdx.x;                          // 256 = 8b * 2ot * 16pt
  int b  = bid >> 5;
  int ot = (bid >> 4) & 1;
  int pt = bid & 15;
  int y0 = pt * 4, obase = ot * 256;
  int tid = threadIdx.x;                         // 512
  int wave = tid >> 6, lane = tid & 63;
  int wm = wave >> 2, wn = wave & 3;             // 2 o-halves x 4 y-rows
  int col0 = lane & 15, kg = lane >> 4;

  // A-stage: thread covers chunks c=tid, tid+512 of the 1024x16B tile
  int kgr0 = tid >> 8;                           // 0..1
  int o_l  = tid & 255;
  const u16* awsrc0 = wmod + ((size_t)((b * 576 + kgr0    ) * 512) + obase + o_l) * 8;
  const u16* awsrc1 = wmod + ((size_t)((b * 576 + kgr0 + 2) * 512) + obase + o_l) * 8;

  // B base: imgt[(b*64+kg)][y0+wn][col0][8]; per-icc advance = 4 grp rows
  const u16* pB = imgt + (((size_t)(b * 64 + kg) * HP + (y0 + wn)) * WPAD + col0) * 8;

  f32x4 zero = {0.f, 0.f, 0.f, 0.f};
  f32x4 acc[8][4];
#pragma unroll
  for (int i = 0; i < 8; ++i)
#pragma unroll
    for (int j = 0; j < 4; ++j) acc[i][j] = zero;

  bf16x8 bregE[4], bregO[4];

#define SLOT(m) ((m) % 3)
#define ICCX(m) (ii2 + ((m) >= 18 ? 2 : ((m) >= 9 ? 1 : 0)))
#define TX(m)   ((m) % 9)

#define STAGE_A(slot, icc, t) do { \
  int aoff_ = ((t) * 64 + (icc) * 4) * 4096; \
  async16(awsrc0 + aoff_, (void*)(abuf[slot] + (size_t)tid * 8)); \
  async16(awsrc1 + aoff_, (void*)(abuf[slot] + (size_t)(tid + 512) * 8)); \
} while (0)

#define BPF(dst, icc, t) do { \
  const u16* pb_ = pB + (size_t)(icc) * (4 * HPW * 8); \
  dst[0] = *(const bf16x8*)(pb_ + (((t)/3) * WPAD +  0 + ((t)%3)) * 8); \
  dst[1] = *(const bf16x8*)(pb_ + (((t)/3) * WPAD + 16 + ((t)%3)) * 8); \
  dst[2] = *(const bf16x8*)(pb_ + (((t)/3) * WPAD + 32 + ((t)%3)) * 8); \
  dst[3] = *(const bf16x8*)(pb_ + (((t)/3) * WPAD + 48 + ((t)%3)) * 8); \
} while (0)

#define COMPUTE(j, BR) do { \
  const u16* ab_ = abuf[SLOT(j)] + ((size_t)kg * 256 + wm * 128 + col0) * 8; \
  bf16x8 a_[8]; \
  _Pragma("unroll") \
  for (int am = 0; am < 8; ++am) a_[am] = *(const bf16x8*)(ab_ + am * 128); \
  __builtin_amdgcn_s_setprio(1); \
  _Pragma("unroll") \
  for (int am = 0; am < 8; ++am) { \
    acc[am][0] = __builtin_amdgcn_mfma_f32_16x16x32_bf16(a_[am], BR[0], acc[am][0], 0, 0, 0); \
    acc[am][1] = __builtin_amdgcn_mfma_f32_16x16x32_bf16(a_[am], BR[1], acc[am][1], 0, 0, 0); \
    acc[am][2] = __builtin_amdgcn_mfma_f32_16x16x32_bf16(a_[am], BR[2], acc[am][2], 0, 0, 0); \
    acc[am][3] = __builtin_amdgcn_mfma_f32_16x16x32_bf16(a_[am], BR[3], acc[am][3], 0, 0, 0); \
  } \
  __builtin_amdgcn_s_setprio(0); \
} while (0)

#define STEP(j, BR_CUR, BR_NXT) do { \
  if (ii < 7 || (j) + 1 < 18) BPF(BR_NXT, ICCX((j)+1), TX((j)+1)); \
  if (ii < 7 || (j) + 2 < 18) STAGE_A(SLOT((j)+2), ICCX((j)+2), TX((j)+2)); \
  COMPUTE(j, BR_CUR); \
  if (ii < 7 || (j) < 17) { \
    if ((j) == 16) { asm volatile("s_waitcnt vmcnt(4)" ::: "memory"); } \
    else           { asm volatile("s_waitcnt vmcnt(6)" ::: "memory"); } \
    __builtin_amdgcn_s_barrier(); \
    __builtin_amdgcn_sched_barrier(0); \
  } \
} while (0)

  // prologue: stage A(k=0), A(k=1); prefetch B(k=0)
  {
    int ii2 = 0;
    STAGE_A(0, 0, 0);
    STAGE_A(1, 0, 1);
    BPF(bregE, 0, 0);
  }
  asm volatile("s_waitcnt vmcnt(6)" ::: "memory");   // A(0)+B older set done
  __builtin_amdgcn_s_barrier();
  __builtin_amdgcn_sched_barrier(0);

  for (int ii = 0; ii < 8; ++ii) {                   // 2 icc per iter, 18 taps
    const int ii2 = 2 * ii;
    STEP(0,  bregE, bregO);  STEP(1,  bregO, bregE);
    STEP(2,  bregE, bregO);  STEP(3,  bregO, bregE);
    STEP(4,  bregE, bregO);  STEP(5,  bregO, bregE);
    STEP(6,  bregE, bregO);  STEP(7,  bregO, bregE);
    STEP(8,  bregE, bregO);  STEP(9,  bregO, bregE);
    STEP(10, bregE, bregO);  STEP(11, bregO, bregE);
    STEP(12, bregE, bregO);  STEP(13, bregO, bregE);
    STEP(14, bregE, bregO);  STEP(15, bregO, bregE);
    STEP(16, bregE, bregO);  STEP(17, bregO, bregE);
  }
#undef STEP
#undef COMPUTE
#undef BPF
#undef STAGE_A
#undef SLOT
#undef ICCX
#undef TX

  int y = y0 + wn;
#pragma unroll
  for (int am = 0; am < 8; ++am) {
    int o = obase + wm * 128 + am * 16 + kg * 4;    // row = (lane>>4)*4 + reg
#pragma unroll
    for (int an = 0; an < 4; ++an) {
      int x = an * 16 + col0;                        // col = lane&15
      float* op = out + (((size_t)(b * CO + o)) * HH + y) * WW + x;
#pragma unroll
      for (int rg = 0; rg < 4; ++rg)
        op[(size_t)rg * HH * WW] = acc[am][an][rg];
    }
  }
}

// ---------------- Fallback (ws too small): naive but correct ------------------
__global__ void k_naive(const float* __restrict__ img, const float* __restrict__ s,
                        const float* __restrict__ weight, const float* __restrict__ sigma,
                        float* __restrict__ out) {
  int bid = blockIdx.x;          // 8*512*64, 64 threads
  int y = bid & 63; int r = bid >> 6; int o = r & 511; int b = r >> 9;
  int x = threadIdx.x;
  float sig = sigma[b * CO + o];
  float acc = 0.f;
  for (int i = 0; i < CIN; ++i) {
    float m = s[b * CIN + i] + 1.0f;
    const float* wp = weight + ((size_t)o * CIN + i) * 9;
    const float* ip = img + ((size_t)(b * CIN + i)) * HH * WW;
#pragma unroll
    for (int ky = 0; ky < 3; ++ky) {
      int yy = y + ky - 1;
      if (yy < 0 || yy > 63) continue;
#pragma unroll
      for (int kx = 0; kx < 3; ++kx) {
        int xx = x + kx - 1;
        float iv = (xx >= 0 && xx < 64) ? ip[yy * 64 + xx] : 0.f;
        acc += wp[ky * 3 + kx] * m * iv;
      }
    }
  }
  out[((size_t)(b * CO + o) * HH + y) * WW + x] = acc * sig;
}

extern "C" void kernel_launch(void* const* d_in, const int* in_sizes, int n_in,
                              void* d_out, int out_size, void* d_ws, size_t ws_size,
                              hipStream_t stream) {
  const float* img    = (const float*)d_in[0];
  const float* s      = (const float*)d_in[1];
  const float* weight = (const float*)d_in[2];
  float* out = (float*)d_out;
  char* ws = (char*)d_ws;
  float* sigma = (float*)ws;

  if (ws_size >= WS_NEED) {
    u16* wmod = (u16*)(ws + SIG_BYTES);
    u16* imgt = (u16*)(ws + SIG_BYTES + WMOD_BYTES);
    k_sigma<<<512, 256, 0, stream>>>(weight, s, sigma);
    k_wmod<<<256, 256, 0, stream>>>(weight, s, sigma, wmod);
    k_pad<<<528, 256, 0, stream>>>(imgt);
    k_imgt<<<8192, 256, 0, stream>>>(img, imgt);
    k_conv<<<256, 512, 0, stream>>>(wmod, imgt, out);
  } else {
    k_sigma<<<512, 256, 0, stream>>>(weight, s, sigma);
    k_naive<<<BB * CO * HH, 64, 0, stream>>>(img, s, weight, sigma, out);
  }
}

// Round 5
// 171.023 us; speedup vs baseline: 1.4003x; 1.0351x over previous
//
#include <hip/hip_runtime.h>

typedef __attribute__((ext_vector_type(8))) short bf16x8;
typedef __attribute__((ext_vector_type(4))) float f32x4;
typedef __attribute__((ext_vector_type(8))) unsigned short u16x8;
typedef unsigned int u32;
typedef unsigned short u16;

#define CIN 512
#define CO  512
#define HH  64
#define WW  64
#define BB  8
#define HP  66
#define WPAD 68
#define HPW (HP*WPAD)
#define KK  4608  // CIN*9

#define SIG_BYTES  (BB*CO*4)                       // 16384
#define WMOD_ELEMS ((size_t)BB*9*64*CO*8)          // 18,874,368
#define WMOD_BYTES (WMOD_ELEMS*2)                  // 37,748,736
#define IMGT_ELEMS ((size_t)BB*64*HP*WPAD*8)       // 18,382,848  [b][grp64][66][68][8]
#define IMGT_BYTES (IMGT_ELEMS*2)                  // 36,765,696
#define WS_NEED    ((size_t)SIG_BYTES + WMOD_BYTES + IMGT_BYTES)

__device__ __forceinline__ u16 f2bf(float f) {
  union { float f; u32 u; } v; v.f = f;
  u32 r = (v.u + 0x7FFFu + ((v.u >> 16) & 1u)) >> 16;  // RNE
  return (u16)r;
}

// ---------------- K1: sigma[b][o] = rsqrt(sum_i,t (w*(s+1))^2 + eps) ----------
__global__ void k_sigma(const float* __restrict__ weight, const float* __restrict__ s,
                        float* __restrict__ sigma) {
  int o = blockIdx.x;          // 512 blocks
  int tid = threadIdx.x;       // 256 threads
  const float* wrow = weight + (size_t)o * KK;
  float acc[BB];
#pragma unroll
  for (int b = 0; b < BB; ++b) acc[b] = 0.f;
  for (int e = tid; e < KK; e += 256) {
    float w = wrow[e];
    float w2 = w * w;
    int i = e / 9;
#pragma unroll
    for (int b = 0; b < BB; ++b) {
      float m = s[b * CIN + i] + 1.0f;
      acc[b] += w2 * m * m;
    }
  }
#pragma unroll
  for (int b = 0; b < BB; ++b) {
#pragma unroll
    for (int off = 32; off >= 1; off >>= 1)
      acc[b] += __shfl_down(acc[b], off);
  }
  __shared__ float red[4][BB];
  int wv = tid >> 6, ln = tid & 63;
  if (ln == 0) {
#pragma unroll
    for (int b = 0; b < BB; ++b) red[wv][b] = acc[b];
  }
  __syncthreads();
  if (tid < BB) {
    float t = red[0][tid] + red[1][tid] + red[2][tid] + red[3][tid];
    sigma[tid * CO + o] = rsqrtf(t + 1e-8f);
  }
}

// ------------- K2: wmod[b][t][kg][o][8] bf16, LDS-staged coalesced ------------
__global__ __launch_bounds__(256) void k_wmod(const float* __restrict__ weight,
                                              const float* __restrict__ s,
                                              const float* __restrict__ sigma,
                                              u16* __restrict__ wmod) {
  __shared__ float lw[16][577];
  int bid = blockIdx.x;        // 256 = 32 oc * 8 ic
  int oc = bid & 31, ic = bid >> 5;
  int o0 = oc * 16;
  int tid = threadIdx.x;
  const float* wsrc = weight + (size_t)o0 * KK + ic * 576;
#pragma unroll
  for (int k = 0; k < 9; ++k) {
    int f4 = tid + k * 256;            // 0..2303
    int row = f4 / 144;                // 144 float4 per row
    int col = f4 - row * 144;
    float4 v = *(const float4*)(wsrc + (size_t)row * KK + col * 4);
    lw[row][col*4+0]=v.x; lw[row][col*4+1]=v.y; lw[row][col*4+2]=v.z; lw[row][col*4+3]=v.w;
  }
  __syncthreads();
  int o_l = tid & 15, kg_l = (tid >> 4) & 7;
#pragma unroll
  for (int k = 0; k < 36; ++k) {
    int bt = k * 2 + (tid >> 7);       // 0..71
    int b = bt / 9;
    int t = bt - b * 9;
    int o = o0 + o_l;
    float sig = sigma[b * CO + o];
    u16x8 ov;
#pragma unroll
    for (int j = 0; j < 8; ++j) {
      int il = kg_l * 8 + j;
      float w = lw[o_l][il * 9 + t];
      float m = s[b * CIN + ic * 64 + il] + 1.0f;
      ov[j] = f2bf(w * m * sig);
    }
    *(u16x8*)(wmod + ((size_t)(bt * 64 + (ic * 8 + kg_l)) * CO + o) * 8) = ov;
  }
}

// ------------- K3a: zero pad border of imgt [b][grp][66][68][8] --------------
__global__ void k_pad(u16* __restrict__ imgt) {
  int gid = blockIdx.x * 256 + threadIdx.x;   // 528*256 = 135168 vec-stores
  int grp = gid & 63;
  int pos = gid >> 6;                         // 0..2111 = 8b * 264
  int b = pos / 264;
  int pr = pos - b * 264;
  int yp, xp;
  if (pr < 136) { yp = (pr < 68) ? 0 : 65; xp = (pr < 68) ? pr : pr - 68; }
  else { int q = pr - 136; yp = 1 + (q >> 1); xp = (q & 1) ? 67 : 0; }
  u16x8 z = {0,0,0,0,0,0,0,0};
  *(u16x8*)(imgt + (((size_t)(b * 64 + grp) * HP + yp) * WPAD + xp) * 8) = z;
}

// ------------- K3b: imgt[b][grp(64)][yp(66)][xp(68)][8ch] bf16, interior ------
__global__ void k_imgt(const float* __restrict__ img, u16* __restrict__ imgt) {
  int bid = blockIdx.x;        // 8*64*2*8 = 8192 blocks
  int ic = bid & 7;  int r = bid >> 3;
  int xc = r & 1;    r >>= 1;
  int y  = r & 63;   int b = r >> 6;
  int tid = threadIdx.x;
  __shared__ float lt[64][33];
  {
    int ii = tid >> 2, xq = tid & 3;
    const float* src = img + (((size_t)(b * CIN + ic * 64 + ii)) * HH + y) * WW + xc * 32 + xq * 8;
    float4 v0 = *(const float4*)src;
    float4 v1 = *(const float4*)(src + 4);
    int xb = xq * 8;
    lt[ii][xb+0]=v0.x; lt[ii][xb+1]=v0.y; lt[ii][xb+2]=v0.z; lt[ii][xb+3]=v0.w;
    lt[ii][xb+4]=v1.x; lt[ii][xb+5]=v1.y; lt[ii][xb+6]=v1.z; lt[ii][xb+7]=v1.w;
  }
  __syncthreads();
  int xl = tid >> 3, iq = tid & 7;
  u16x8 ov;
#pragma unroll
  for (int j = 0; j < 8; ++j) ov[j] = f2bf(lt[iq*8+j][xl]);
  size_t dst = (((size_t)(b * 64 + ic * 8 + iq) * HP + (y + 1)) * WPAD + (xc * 32 + xl + 1)) * 8;
  *(u16x8*)(imgt + dst) = ov;
}

// ------- K4: implicit-GEMM conv: 3-tap groups, A dbuf LDS, B reg prefetch -----
__device__ __forceinline__ void async16(const u16* g, void* lds) {
  __builtin_amdgcn_global_load_lds((const __attribute__((address_space(1))) u32*)g,
                                   (__attribute__((address_space(3))) u32*)lds, 16, 0, 0);
}

__global__ __launch_bounds__(512, 2) void k_conv(const u16* __restrict__ wmod,
                                                 const u16* __restrict__ imgt,
                                                 float* __restrict__ out) {
  __shared__ alignas(16) u16 abuf[2][3][8192];   // 2 x (3 taps x 16KB) = 96KB
  int bid0 = blockIdx.x;                          // 256 = 8b * 2ot * 16pt
  int bid  = (bid0 & 7) * 32 + (bid0 >> 3);       // XCD-chunked: each XCD = one b
  int b  = bid >> 5;
  int ot = (bid >> 4) & 1;
  int pt = bid & 15;
  int y0 = pt * 4, obase = ot * 256;
  int tid = threadIdx.x;                          // 512
  int wave = tid >> 6, lane = tid & 63;
  int wm = wave >> 2, wn = wave & 3;              // 2 o-halves x 4 y-rows
  int col0 = lane & 15, kg = lane >> 4;

  // A-stage source: thread covers chunks tid (kg4=tid>>8) and tid+512 (kg4+2)
  const u16* awsrc0 = wmod + (((size_t)(b * 576 + (tid >> 8))) * 512 + obase + (tid & 255)) * 8;
  const u16* awsrc1 = awsrc0 + 2 * 512 * 8;

  // B base: imgt[(b*64+kg)][y0+wn][col0][8]; per-icc advance = 4 grp rows
  const u16* pB = imgt + (((size_t)(b * 64 + kg) * HP + (y0 + wn)) * WPAD + col0) * 8;

  f32x4 zero = {0.f, 0.f, 0.f, 0.f};
  f32x4 acc[8][4];
#pragma unroll
  for (int i = 0; i < 8; ++i)
#pragma unroll
    for (int j = 0; j < 4; ++j) acc[i][j] = zero;

  bf16x8 bregE[4], bregO[4];

#define STAGE3(slot, iccv, rv) do { \
  _Pragma("unroll") \
  for (int c_ = 0; c_ < 3; ++c_) { \
    int aoff_ = ((3 * (rv) + c_) * 64 + (iccv) * 4) * 4096; \
    async16(awsrc0 + aoff_, (void*)(&abuf[slot][c_][0] + (size_t)tid * 8)); \
    async16(awsrc1 + aoff_, (void*)(&abuf[slot][c_][0] + (size_t)(tid + 512) * 8)); \
  } } while (0)

#define BPF(dst, iccv, tv) do { \
  const u16* pb_ = pB + (size_t)(iccv) * (4 * HPW * 8); \
  dst[0] = *(const bf16x8*)(pb_ + (((tv)/3) * WPAD +  0 + ((tv)%3)) * 8); \
  dst[1] = *(const bf16x8*)(pb_ + (((tv)/3) * WPAD + 16 + ((tv)%3)) * 8); \
  dst[2] = *(const bf16x8*)(pb_ + (((tv)/3) * WPAD + 32 + ((tv)%3)) * 8); \
  dst[3] = *(const bf16x8*)(pb_ + (((tv)/3) * WPAD + 48 + ((tv)%3)) * 8); \
} while (0)

#define COMPUTE(slot, c_, BR) do { \
  const u16* ab_ = &abuf[slot][c_][(kg * 256 + wm * 128 + col0) * 8]; \
  bf16x8 a_[8]; \
  _Pragma("unroll") \
  for (int am = 0; am < 8; ++am) a_[am] = *(const bf16x8*)(ab_ + am * 128); \
  __builtin_amdgcn_s_setprio(1); \
  _Pragma("unroll") \
  for (int am = 0; am < 8; ++am) { \
    acc[am][0] = __builtin_amdgcn_mfma_f32_16x16x32_bf16(a_[am], BR[0], acc[am][0], 0, 0, 0); \
    acc[am][1] = __builtin_amdgcn_mfma_f32_16x16x32_bf16(a_[am], BR[1], acc[am][1], 0, 0, 0); \
    acc[am][2] = __builtin_amdgcn_mfma_f32_16x16x32_bf16(a_[am], BR[2], acc[am][2], 0, 0, 0); \
    acc[am][3] = __builtin_amdgcn_mfma_f32_16x16x32_bf16(a_[am], BR[3], acc[am][3], 0, 0, 0); \
  } \
  __builtin_amdgcn_s_setprio(0); \
} while (0)

// group g (0..5) within an ii (2 icc); taps j = 3g..3g+2; B parity B0,B1,B0
#define GROUP(g, B0, B1) do { \
  if (ii < 7 || (g) < 5) STAGE3((((g) + 1) & 1), ii2 + ((g) + 1) / 3, ((g) + 1) % 3); \
  BPF(B1, ii2 + (3 * (g) + 1) / 9, (3 * (g) + 1) % 9); \
  COMPUTE(((g) & 1), 0, B0); \
  BPF(B0, ii2 + (3 * (g) + 2) / 9, (3 * (g) + 2) % 9); \
  COMPUTE(((g) & 1), 1, B1); \
  if (ii < 7 || 3 * (g) + 3 < 18) BPF(B1, ii2 + (3 * (g) + 3) / 9, (3 * (g) + 3) % 9); \
  COMPUTE(((g) & 1), 2, B0); \
  asm volatile("s_waitcnt vmcnt(12)" ::: "memory"); \
  __builtin_amdgcn_s_barrier(); \
  __builtin_amdgcn_sched_barrier(0); \
} while (0)

  // prologue: stage group 0 (slot 0), prefetch B(tap 0)
  {
    const int ii2 = 0;
    STAGE3(0, 0, 0);
    BPF(bregE, 0, 0);
  }
  asm volatile("s_waitcnt vmcnt(4)" ::: "memory");   // 6 stage loads (oldest) done
  __builtin_amdgcn_s_barrier();
  __builtin_amdgcn_sched_barrier(0);

  for (int ii = 0; ii < 8; ++ii) {                   // 2 icc (= 6 groups, 18 taps)
    const int ii2 = 2 * ii;
    GROUP(0, bregE, bregO);
    GROUP(1, bregO, bregE);
    GROUP(2, bregE, bregO);
    GROUP(3, bregO, bregE);
    GROUP(4, bregE, bregO);
    GROUP(5, bregO, bregE);
  }
#undef GROUP
#undef COMPUTE
#undef BPF
#undef STAGE3

  int y = y0 + wn;
#pragma unroll
  for (int am = 0; am < 8; ++am) {
    int o = obase + wm * 128 + am * 16 + kg * 4;    // row = (lane>>4)*4 + reg
#pragma unroll
    for (int an = 0; an < 4; ++an) {
      int x = an * 16 + col0;                        // col = lane&15
      float* op = out + (((size_t)(b * CO + o)) * HH + y) * WW + x;
#pragma unroll
      for (int rg = 0; rg < 4; ++rg)
        op[(size_t)rg * HH * WW] = acc[am][an][rg];
    }
  }
}

// ---------------- Fallback (ws too small): naive but correct ------------------
__global__ void k_naive(const float* __restrict__ img, const float* __restrict__ s,
                        const float* __restrict__ weight, const float* __restrict__ sigma,
                        float* __restrict__ out) {
  int bid = blockIdx.x;          // 8*512*64, 64 threads
  int y = bid & 63; int r = bid >> 6; int o = r & 511; int b = r >> 9;
  int x = threadIdx.x;
  float sig = sigma[b * CO + o];
  float acc = 0.f;
  for (int i = 0; i < CIN; ++i) {
    float m = s[b * CIN + i] + 1.0f;
    const float* wp = weight + ((size_t)o * CIN + i) * 9;
    const float* ip = img + ((size_t)(b * CIN + i)) * HH * WW;
#pragma unroll
    for (int ky = 0; ky < 3; ++ky) {
      int yy = y + ky - 1;
      if (yy < 0 || yy > 63) continue;
#pragma unroll
      for (int kx = 0; kx < 3; ++kx) {
        int xx = x + kx - 1;
        float iv = (xx >= 0 && xx < 64) ? ip[yy * 64 + xx] : 0.f;
        acc += wp[ky * 3 + kx] * m * iv;
      }
    }
  }
  out[((size_t)(b * CO + o) * HH + y) * WW + x] = acc * sig;
}

extern "C" void kernel_launch(void* const* d_in, const int* in_sizes, int n_in,
                              void* d_out, int out_size, void* d_ws, size_t ws_size,
                              hipStream_t stream) {
  const float* img    = (const float*)d_in[0];
  const float* s      = (const float*)d_in[1];
  const float* weight = (const float*)d_in[2];
  float* out = (float*)d_out;
  char* ws = (char*)d_ws;
  float* sigma = (float*)ws;

  if (ws_size >= WS_NEED) {
    u16* wmod = (u16*)(ws + SIG_BYTES);
    u16* imgt = (u16*)(ws + SIG_BYTES + WMOD_BYTES);
    k_sigma<<<512, 256, 0, stream>>>(weight, s, sigma);
    k_wmod<<<256, 256, 0, stream>>>(weight, s, sigma, wmod);
    k_pad<<<528, 256, 0, stream>>>(imgt);
    k_imgt<<<8192, 256, 0, stream>>>(img, imgt);
    k_conv<<<256, 512, 0, stream>>>(wmod, imgt, out);
  } else {
    k_sigma<<<512, 256, 0, stream>>>(weight, s, sigma);
    k_naive<<<BB * CO * HH, 64, 0, stream>>>(img, s, weight, sigma, out);
  }
}